// Round 1
// baseline (784.097 us; speedup 1.0000x reference)
//
#include <hip/hip_runtime.h>
#include <math.h>

#define BB 2
#define TT 2048
#define DD 1024
#define HH 16
#define DHEAD 64
#define BT (BB*TT)   // 4096

// ---------------- tiled fp32 GEMM: C[.,N] = A[.,K] @ W[N,K]^T (+bias) ------
// 64x64 tile, BK=16, 256 threads, 4x4 per thread.
__device__ __forceinline__ void gemm_body(const float* __restrict__ A,
                                          const float* __restrict__ W,
                                          const float* __restrict__ bias,
                                          float* __restrict__ C,
                                          int N, int K, int bm, int bn) {
    constexpr int BK = 16;
    __shared__ __attribute__((aligned(16))) float As[BK][68];
    __shared__ __attribute__((aligned(16))) float Ws[BK][68];
    const int tid = threadIdx.x;
    const int tr = (tid >> 4) << 2;   // 0..60
    const int tc = (tid & 15) << 2;   // 0..60
    const int lr = tid >> 2;          // 0..63
    const int lk = (tid & 3) << 2;    // 0,4,8,12
    float acc[4][4] = {};
    const float* Ap = A + (size_t)(bm + lr) * K + lk;
    const float* Wp = W + (size_t)(bn + lr) * K + lk;
    for (int k0 = 0; k0 < K; k0 += BK) {
        float4 a4 = *(const float4*)(Ap + k0);
        float4 w4 = *(const float4*)(Wp + k0);
        As[lk+0][lr] = a4.x; As[lk+1][lr] = a4.y; As[lk+2][lr] = a4.z; As[lk+3][lr] = a4.w;
        Ws[lk+0][lr] = w4.x; Ws[lk+1][lr] = w4.y; Ws[lk+2][lr] = w4.z; Ws[lk+3][lr] = w4.w;
        __syncthreads();
        #pragma unroll
        for (int kk = 0; kk < BK; ++kk) {
            float4 av = *(const float4*)&As[kk][tr];
            float4 wv = *(const float4*)&Ws[kk][tc];
            float a_[4] = {av.x, av.y, av.z, av.w};
            float w_[4] = {wv.x, wv.y, wv.z, wv.w};
            #pragma unroll
            for (int i = 0; i < 4; ++i)
                #pragma unroll
                for (int j = 0; j < 4; ++j)
                    acc[i][j] += a_[i] * w_[j];
        }
        __syncthreads();
    }
    #pragma unroll
    for (int i = 0; i < 4; ++i) {
        #pragma unroll
        for (int j = 0; j < 4; ++j) {
            float v = acc[i][j];
            if (bias) v += bias[bn + tc + j];
            C[(size_t)(bm + tr + i) * N + bn + tc + j] = v;
        }
    }
}

__global__ __launch_bounds__(256) void gemm_kernel(const float* __restrict__ A,
                                                   const float* __restrict__ W,
                                                   const float* __restrict__ bias,
                                                   float* __restrict__ C,
                                                   int N, int K) {
    gemm_body(A, W, bias, C, N, K, blockIdx.x * 64, blockIdx.y * 64);
}

// batched q/k projections: grid.z picks which weight; outputs contiguous
__global__ __launch_bounds__(256) void gemm_qk_kernel(const float* __restrict__ x,
                                                      const float* __restrict__ W1,
                                                      const float* __restrict__ W2,
                                                      const float* __restrict__ W3,
                                                      const float* __restrict__ W4,
                                                      float* __restrict__ out4) {
    const int z = blockIdx.z;
    const float* W = (z == 0) ? W1 : (z == 1) ? W2 : (z == 2) ? W3 : W4;
    float* C = out4 + (size_t)z * BT * 64;
    gemm_body(x, W, nullptr, C, 64, DD, blockIdx.x * 64, 0);
}

// ---------------- exterior (Plucker) + normalize; fold J6 & scale into K --
__device__ __forceinline__ void ext6(const float* a, const float* b, float* L) {
    L[0] = a[0]*b[1] - a[1]*b[0];
    L[1] = a[0]*b[2] - a[2]*b[0];
    L[2] = a[0]*b[3] - a[3]*b[0];
    L[3] = a[1]*b[2] - a[2]*b[1];
    L[4] = a[1]*b[3] - a[3]*b[1];
    L[5] = a[2]*b[3] - a[3]*b[2];
}

__global__ __launch_bounds__(256) void exterior_kernel(const float* __restrict__ q1,
                                                       const float* __restrict__ q2,
                                                       const float* __restrict__ k1,
                                                       const float* __restrict__ k2,
                                                       float* __restrict__ Lq,
                                                       float* __restrict__ JK) {
    int idx = blockIdx.x * 256 + threadIdx.x;     // over BT*HH
    if (idx >= BT * HH) return;
    int bt = idx >> 4, h = idx & 15;
    size_t base = (size_t)bt * 64 + h * 4;
    float a[4], b[4], L[6];
    #pragma unroll
    for (int i = 0; i < 4; ++i) { a[i] = q1[base + i]; b[i] = q2[base + i]; }
    ext6(a, b, L);
    float s = 0.f;
    #pragma unroll
    for (int c = 0; c < 6; ++c) s += L[c] * L[c];
    float inv = 1.0f / fmaxf(sqrtf(s), 1e-12f);
    #pragma unroll
    for (int c = 0; c < 6; ++c) Lq[(size_t)idx * 6 + c] = L[c] * inv;

    #pragma unroll
    for (int i = 0; i < 4; ++i) { a[i] = k1[base + i]; b[i] = k2[base + i]; }
    ext6(a, b, L);
    s = 0.f;
    #pragma unroll
    for (int c = 0; c < 6; ++c) s += L[c] * L[c];
    const float SCALE = 0.40824829046386307f;     // 6^-0.5
    inv = SCALE / fmaxf(sqrtf(s), 1e-12f);
    // JL_k = [L5, -L4, L3, L2, -L1, L0] * SCALE / norm
    float* o = JK + (size_t)idx * 6;
    o[0] =  L[5] * inv;
    o[1] = -L[4] * inv;
    o[2] =  L[3] * inv;
    o[3] =  L[2] * inv;
    o[4] = -L[1] * inv;
    o[5] =  L[0] * inv;
}

// ---------------- flash attention -----------------------------------------
// grid (T/16, B*H); 256 threads = 4 waves; wave w owns q rows q0+4w..q0+4w+3
__global__ __launch_bounds__(256) void flash_kernel(const float* __restrict__ Lq,
                                                    const float* __restrict__ JK,
                                                    const float* __restrict__ V,
                                                    float* __restrict__ O) {
    const int qb = blockIdx.x, bh = blockIdx.y;
    const int b = bh >> 4, h = bh & 15;
    const int tid = threadIdx.x, w = tid >> 6, lane = tid & 63;
    const int q0 = qb * 16;
    __shared__ __attribute__((aligned(16))) float jk_s[6][64];
    __shared__ __attribute__((aligned(16))) float vs[64][64];      // 16 KB
    __shared__ __attribute__((aligned(16))) float p_s[4][64][4];   // [wave][key][row]

    float lq[4][6];
    int qrow[4];
    #pragma unroll
    for (int r = 0; r < 4; ++r) {
        qrow[r] = q0 + w * 4 + r;
        const float* p = Lq + ((size_t)(b * TT + qrow[r]) * HH + h) * 6;
        #pragma unroll
        for (int c = 0; c < 6; ++c) lq[r][c] = p[c];
    }
    float m[4] = {-INFINITY, -INFINITY, -INFINITY, -INFINITY};
    float l[4] = {0.f, 0.f, 0.f, 0.f};
    float acc[4] = {0.f, 0.f, 0.f, 0.f};          // dim = lane

    const int ntiles = (q0 + 15) / 64 + 1;
    for (int t = 0; t < ntiles; ++t) {
        const int k0 = t << 6;
        // stage JK^T tile: jk_s[c][key]
        for (int i = tid; i < 6 * 64; i += 256) {
            int c = i >> 6, key = i & 63;
            jk_s[c][key] = JK[((size_t)(b * TT + k0 + key) * HH + h) * 6 + c];
        }
        // stage V tile: vs[key][d]
        #pragma unroll
        for (int rep = 0; rep < 4; ++rep) {
            int key = (tid >> 4) + rep * 16;
            int d = (tid & 15) << 2;
            *(float4*)&vs[key][d] =
                *(const float4*)(V + (size_t)(b * TT + k0 + key) * DD + h * DHEAD + d);
        }
        __syncthreads();

        // phase 1: lane = key
        #pragma unroll
        for (int r = 0; r < 4; ++r) {
            float s = lq[r][0] * jk_s[0][lane] + lq[r][1] * jk_s[1][lane]
                    + lq[r][2] * jk_s[2][lane] + lq[r][3] * jk_s[3][lane]
                    + lq[r][4] * jk_s[4][lane] + lq[r][5] * jk_s[5][lane];
            int k = k0 + lane;
            s = (k <= qrow[r]) ? s : -INFINITY;
            float tmax = s;
            #pragma unroll
            for (int off = 32; off; off >>= 1)
                tmax = fmaxf(tmax, __shfl_xor(tmax, off));
            float mn = fmaxf(m[r], tmax);
            float p = __expf(s - mn);
            float al = __expf(m[r] - mn);
            float ps = p;
            #pragma unroll
            for (int off = 32; off; off >>= 1)
                ps += __shfl_xor(ps, off);
            l[r] = l[r] * al + ps;
            acc[r] *= al;
            m[r] = mn;
            p_s[w][lane][r] = p;
        }
        __syncthreads();

        // phase 2: lane = dim
        #pragma unroll 8
        for (int kk = 0; kk < 64; ++kk) {
            float4 pr = *(const float4*)&p_s[w][kk][0];
            float vv = vs[kk][lane];
            acc[0] += pr.x * vv;
            acc[1] += pr.y * vv;
            acc[2] += pr.z * vv;
            acc[3] += pr.w * vv;
        }
        __syncthreads();
    }
    #pragma unroll
    for (int r = 0; r < 4; ++r)
        O[(size_t)(b * TT + qrow[r]) * DD + h * DHEAD + lane] = acc[r] / l[r];
}

extern "C" void kernel_launch(void* const* d_in, const int* in_sizes, int n_in,
                              void* d_out, int out_size, void* d_ws, size_t ws_size,
                              hipStream_t stream) {
    const float* x    = (const float*)d_in[0];
    const float* W1q  = (const float*)d_in[1];
    const float* W2q  = (const float*)d_in[2];
    const float* W1k  = (const float*)d_in[3];
    const float* W2k  = (const float*)d_in[4];
    const float* Wv   = (const float*)d_in[5];
    const float* bv   = (const float*)d_in[6];
    const float* Wout = (const float*)d_in[7];
    const float* bout = (const float*)d_in[8];
    float* out = (float*)d_out;

    float* ws  = (float*)d_ws;
    float* q1  = ws;                                  // 4 * BT*64
    float* Lq  = q1 + 4 * (size_t)BT * 64;            // BT*H*6
    float* JK  = Lq + (size_t)BT * HH * 6;            // BT*H*6
    float* V   = JK + (size_t)BT * HH * 6;            // BT*D
    float* AO  = V  + (size_t)BT * DD;                // BT*D

    // 1. q1,q2,k1,k2 projections (batched over grid.z)
    gemm_qk_kernel<<<dim3(BT / 64, 1, 4), 256, 0, stream>>>(x, W1q, W2q, W1k, W2k, q1);
    // 2. Plucker lines (+ J6 & scale folded into K side)
    exterior_kernel<<<dim3(BT * HH / 256), 256, 0, stream>>>(
        q1, q1 + (size_t)BT * 64, q1 + 2 * (size_t)BT * 64, q1 + 3 * (size_t)BT * 64, Lq, JK);
    // 3. v projection
    gemm_kernel<<<dim3(BT / 64, DD / 64), 256, 0, stream>>>(x, Wv, bv, V, DD, DD);
    // 4. causal flash attention
    flash_kernel<<<dim3(TT / 16, BB * HH), 256, 0, stream>>>(Lq, JK, V, AO);
    // 5. output projection
    gemm_kernel<<<dim3(BT / 64, DD / 64), 256, 0, stream>>>(AO, Wout, bout, out, DD, DD);
}

// Round 2
// 375.493 us; speedup vs baseline: 2.0882x; 2.0882x over previous
//
#include <hip/hip_runtime.h>
#include <math.h>

#define BB 2
#define TT 2048
#define DD 1024
#define HH 16
#define DHEAD 64
#define BT (BB*TT)   // 4096

typedef __attribute__((ext_vector_type(4))) _Float16 f16x4;
typedef __attribute__((ext_vector_type(4))) float f32x4;

// ---------------- tiled fp32 GEMM: C[.,N] = A[.,K] @ W[N,K]^T (+bias) ------
// 64x64 tile, BK=16, 256 threads, 4x4 per thread.
__device__ __forceinline__ void gemm_body(const float* __restrict__ A,
                                          const float* __restrict__ W,
                                          const float* __restrict__ bias,
                                          float* __restrict__ C,
                                          int N, int K, int bm, int bn) {
    constexpr int BK = 16;
    __shared__ __attribute__((aligned(16))) float As[BK][68];
    __shared__ __attribute__((aligned(16))) float Ws[BK][68];
    const int tid = threadIdx.x;
    const int tr = (tid >> 4) << 2;   // 0..60
    const int tc = (tid & 15) << 2;   // 0..60
    const int lr = tid >> 2;          // 0..63
    const int lk = (tid & 3) << 2;    // 0,4,8,12
    float acc[4][4] = {};
    const float* Ap = A + (size_t)(bm + lr) * K + lk;
    const float* Wp = W + (size_t)(bn + lr) * K + lk;
    for (int k0 = 0; k0 < K; k0 += BK) {
        float4 a4 = *(const float4*)(Ap + k0);
        float4 w4 = *(const float4*)(Wp + k0);
        As[lk+0][lr] = a4.x; As[lk+1][lr] = a4.y; As[lk+2][lr] = a4.z; As[lk+3][lr] = a4.w;
        Ws[lk+0][lr] = w4.x; Ws[lk+1][lr] = w4.y; Ws[lk+2][lr] = w4.z; Ws[lk+3][lr] = w4.w;
        __syncthreads();
        #pragma unroll
        for (int kk = 0; kk < BK; ++kk) {
            float4 av = *(const float4*)&As[kk][tr];
            float4 wv = *(const float4*)&Ws[kk][tc];
            float a_[4] = {av.x, av.y, av.z, av.w};
            float w_[4] = {wv.x, wv.y, wv.z, wv.w};
            #pragma unroll
            for (int i = 0; i < 4; ++i)
                #pragma unroll
                for (int j = 0; j < 4; ++j)
                    acc[i][j] += a_[i] * w_[j];
        }
        __syncthreads();
    }
    #pragma unroll
    for (int i = 0; i < 4; ++i) {
        #pragma unroll
        for (int j = 0; j < 4; ++j) {
            float v = acc[i][j];
            if (bias) v += bias[bn + tc + j];
            C[(size_t)(bm + tr + i) * N + bn + tc + j] = v;
        }
    }
}

__global__ __launch_bounds__(256) void gemm_kernel(const float* __restrict__ A,
                                                   const float* __restrict__ W,
                                                   const float* __restrict__ bias,
                                                   float* __restrict__ C,
                                                   int N, int K) {
    gemm_body(A, W, bias, C, N, K, blockIdx.x * 64, blockIdx.y * 64);
}

// batched q/k projections: grid.z picks which weight; outputs contiguous
__global__ __launch_bounds__(256) void gemm_qk_kernel(const float* __restrict__ x,
                                                      const float* __restrict__ W1,
                                                      const float* __restrict__ W2,
                                                      const float* __restrict__ W3,
                                                      const float* __restrict__ W4,
                                                      float* __restrict__ out4) {
    const int z = blockIdx.z;
    const float* W = (z == 0) ? W1 : (z == 1) ? W2 : (z == 2) ? W3 : W4;
    float* C = out4 + (size_t)z * BT * 64;
    gemm_body(x, W, nullptr, C, 64, DD, blockIdx.x * 64, 0);
}

// ---------------- exterior (Plucker) + normalize; fold J6 & scale into K --
// Output layout: [b][h][t][6]  (contiguous per (b,h) for flash staging)
__device__ __forceinline__ void ext6(const float* a, const float* b, float* L) {
    L[0] = a[0]*b[1] - a[1]*b[0];
    L[1] = a[0]*b[2] - a[2]*b[0];
    L[2] = a[0]*b[3] - a[3]*b[0];
    L[3] = a[1]*b[2] - a[2]*b[1];
    L[4] = a[1]*b[3] - a[3]*b[1];
    L[5] = a[2]*b[3] - a[3]*b[2];
}

__global__ __launch_bounds__(256) void exterior_kernel(const float* __restrict__ q1,
                                                       const float* __restrict__ q2,
                                                       const float* __restrict__ k1,
                                                       const float* __restrict__ k2,
                                                       float* __restrict__ Lq,
                                                       float* __restrict__ JK) {
    int idx = blockIdx.x * 256 + threadIdx.x;     // over BT*HH
    if (idx >= BT * HH) return;
    int bt = idx >> 4, h = idx & 15;
    int b = bt >> 11, t = bt & (TT - 1);
    size_t obase = ((size_t)(b * HH + h) * TT + t) * 6;
    size_t base = (size_t)bt * 64 + h * 4;
    float a[4], bb[4], L[6];
    #pragma unroll
    for (int i = 0; i < 4; ++i) { a[i] = q1[base + i]; bb[i] = q2[base + i]; }
    ext6(a, bb, L);
    float s = 0.f;
    #pragma unroll
    for (int c = 0; c < 6; ++c) s += L[c] * L[c];
    float inv = 1.0f / fmaxf(sqrtf(s), 1e-12f);
    #pragma unroll
    for (int c = 0; c < 6; ++c) Lq[obase + c] = L[c] * inv;

    #pragma unroll
    for (int i = 0; i < 4; ++i) { a[i] = k1[base + i]; bb[i] = k2[base + i]; }
    ext6(a, bb, L);
    s = 0.f;
    #pragma unroll
    for (int c = 0; c < 6; ++c) s += L[c] * L[c];
    const float SCALE = 0.40824829046386307f;     // 6^-0.5
    inv = SCALE / fmaxf(sqrtf(s), 1e-12f);
    // JL_k = [L5, -L4, L3, L2, -L1, L0] * SCALE / norm
    float* o = JK + obase;
    o[0] =  L[5] * inv;
    o[1] = -L[4] * inv;
    o[2] =  L[3] * inv;
    o[3] =  L[2] * inv;
    o[4] = -L[1] * inv;
    o[5] =  L[0] * inv;
}

// ---------------- MFMA flash attention ------------------------------------
// grid (TT/64, B*H); 256 thr = 4 waves; wave w owns q rows q0+16w..+15.
// No online max needed: |score| <= 6^-0.5 (normalized Plucker lines), so
// p = exp(s) is bounded by e^0.41; lsum accumulates in fp32.
// Score MFMA computes S^T (A=JK rows=keys, B=Lq^T); its C/D layout IS the
// B-fragment layout of the next 16x16x16 MFMA, so P^T stays in registers.
__global__ __launch_bounds__(256) void flash_mfma_kernel(const float* __restrict__ Lq,
                                                         const float* __restrict__ JK,
                                                         const float* __restrict__ V,
                                                         float* __restrict__ O) {
    const int qb = blockIdx.x;
    const int bh = blockIdx.y;            // b*16 + h
    const int b = bh >> 4, h = bh & 15;
    const int tid = threadIdx.x;
    const int w = tid >> 6, lane = tid & 63;
    const int la = lane >> 4, lb = lane & 15;
    const int q0 = qb * 64;
    const int qw = q0 + w * 16;           // wave's q base (col q = qw + lb)

    __shared__ __attribute__((aligned(16))) _Float16 jk_s[64][8];   // [key][c], c6,7=0
    __shared__ __attribute__((aligned(16))) _Float16 vt_s[64 * 64]; // [d][key^swz]
    __shared__ __attribute__((aligned(16))) _Float16 zrow[8];

    if (tid < 8) zrow[tid] = (_Float16)0.f;
    for (int i = tid; i < 64; i += 256) { jk_s[i][6] = (_Float16)0.f; jk_s[i][7] = (_Float16)0.f; }

    // B-operand: Lq^T. col q = qw+lb, k = c = la*4+j (c>=6 zero)
    f16x4 blq = {(_Float16)0.f, (_Float16)0.f, (_Float16)0.f, (_Float16)0.f};
    {
        const float* p = Lq + ((size_t)bh * TT + qw + lb) * 6;
        if (la == 0) { blq[0] = (_Float16)p[0]; blq[1] = (_Float16)p[1];
                       blq[2] = (_Float16)p[2]; blq[3] = (_Float16)p[3]; }
        else if (la == 1) { blq[0] = (_Float16)p[4]; blq[1] = (_Float16)p[5]; }
    }

    f32x4 acc[4] = {};                    // O^T: d = m*16+la*4+i, q = qw+lb
    float lsum = 0.f;
    const int qmask = qw + lb;            // this lane's q row

    const int vkey = tid >> 2;            // V staging: row
    const int vcb  = (tid & 3) * 16;      // V staging: col base

    const int ntiles = qb + 1;
    for (int t = 0; t < ntiles; ++t) {
        const int k0 = t * 64;
        // stage JK tile: 384 contiguous floats -> f16
        const float* jkg = JK + ((size_t)bh * TT + k0) * 6;
        for (int i = tid; i < 384; i += 256) {
            int key = i / 6, c = i - key * 6;
            jk_s[key][c] = (_Float16)jkg[i];
        }
        // stage V tile transposed + XOR-swizzled (T2): vt[d][key ^ ((d&7)<<3)]
        {
            const float* vg = V + (size_t)(b * TT + k0 + vkey) * DD + h * DHEAD + vcb;
            #pragma unroll
            for (int jj = 0; jj < 4; ++jj) {
                float4 v4 = *(const float4*)(vg + jj * 4);
                int d0 = vcb + jj * 4;
                vt_s[(d0+0)*64 + (vkey ^ (((d0+0)&7)<<3))] = (_Float16)v4.x;
                vt_s[(d0+1)*64 + (vkey ^ (((d0+1)&7)<<3))] = (_Float16)v4.y;
                vt_s[(d0+2)*64 + (vkey ^ (((d0+2)&7)<<3))] = (_Float16)v4.z;
                vt_s[(d0+3)*64 + (vkey ^ (((d0+3)&7)<<3))] = (_Float16)v4.w;
            }
        }
        __syncthreads();

        #pragma unroll
        for (int n = 0; n < 4; ++n) {
            if (k0 + n * 16 <= qw + 15) {            // wave-uniform causal skip
                // A-operand: JK, row = key = n*16+lb, k = c
                const _Float16* ap = (la < 2) ? &jk_s[n * 16 + lb][la * 4] : zrow;
                f16x4 ajk = *(const f16x4*)ap;
                f32x4 st = __builtin_amdgcn_mfma_f32_16x16x16f16(
                    ajk, blq, (f32x4){0.f, 0.f, 0.f, 0.f}, 0, 0, 0);
                // st[i] = S^T[key=k0+n*16+la*4+i][q=qw+lb]
                f16x4 pt;
                #pragma unroll
                for (int i = 0; i < 4; ++i) {
                    int key = k0 + n * 16 + la * 4 + i;
                    float p = __expf(st[i]);
                    p = (key <= qmask) ? p : 0.f;
                    lsum += p;
                    pt[i] = (_Float16)p;
                }
                // PV: O^T += V^T (16d x 16k) @ P^T (16k x 16q)
                #pragma unroll
                for (int m = 0; m < 4; ++m) {
                    int d = m * 16 + lb;
                    const _Float16* vp = &vt_s[d * 64 + ((n * 16 + la * 4) ^ ((d & 7) << 3))];
                    f16x4 av = *(const f16x4*)vp;
                    acc[m] = __builtin_amdgcn_mfma_f32_16x16x16f16(av, pt, acc[m], 0, 0, 0);
                }
            }
        }
        __syncthreads();
    }

    // final l reduction across the 4 la-groups holding the same q
    lsum += __shfl_xor(lsum, 16);
    lsum += __shfl_xor(lsum, 32);
    float inv = 1.f / lsum;
    const int q = qw + lb;
    #pragma unroll
    for (int m = 0; m < 4; ++m) {
        float4 o4 = { acc[m][0] * inv, acc[m][1] * inv, acc[m][2] * inv, acc[m][3] * inv };
        *(float4*)&O[(size_t)(b * TT + q) * DD + h * DHEAD + m * 16 + la * 4] = o4;
    }
}

extern "C" void kernel_launch(void* const* d_in, const int* in_sizes, int n_in,
                              void* d_out, int out_size, void* d_ws, size_t ws_size,
                              hipStream_t stream) {
    const float* x    = (const float*)d_in[0];
    const float* W1q  = (const float*)d_in[1];
    const float* W2q  = (const float*)d_in[2];
    const float* W1k  = (const float*)d_in[3];
    const float* W2k  = (const float*)d_in[4];
    const float* Wv   = (const float*)d_in[5];
    const float* bv   = (const float*)d_in[6];
    const float* Wout = (const float*)d_in[7];
    const float* bout = (const float*)d_in[8];
    float* out = (float*)d_out;

    float* ws  = (float*)d_ws;
    float* q1  = ws;                                  // 4 * BT*64
    float* Lq  = q1 + 4 * (size_t)BT * 64;            // BT*H*6  ([b][h][t][6])
    float* JK  = Lq + (size_t)BT * HH * 6;            // BT*H*6  ([b][h][t][6])
    float* V   = JK + (size_t)BT * HH * 6;            // BT*D
    float* AO  = V  + (size_t)BT * DD;                // BT*D

    // 1. q1,q2,k1,k2 projections (batched over grid.z)
    gemm_qk_kernel<<<dim3(BT / 64, 1, 4), 256, 0, stream>>>(x, W1q, W2q, W1k, W2k, q1);
    // 2. Plucker lines (+ J6 & scale folded into K side)
    exterior_kernel<<<dim3(BT * HH / 256), 256, 0, stream>>>(
        q1, q1 + (size_t)BT * 64, q1 + 2 * (size_t)BT * 64, q1 + 3 * (size_t)BT * 64, Lq, JK);
    // 3. v projection
    gemm_kernel<<<dim3(BT / 64, DD / 64), 256, 0, stream>>>(x, Wv, bv, V, DD, DD);
    // 4. causal flash attention (f16 MFMA)
    flash_mfma_kernel<<<dim3(TT / 64, BB * HH), 256, 0, stream>>>(Lq, JK, V, AO);
    // 5. output projection
    gemm_kernel<<<dim3(BT / 64, DD / 64), 256, 0, stream>>>(AO, Wout, bout, out, DD, DD);
}

// Round 3
// 154.479 us; speedup vs baseline: 5.0757x; 2.4307x over previous
//
#include <hip/hip_runtime.h>
#include <math.h>

#define BB 2
#define TT 2048
#define DD 1024
#define HH 16
#define DHEAD 64
#define BT (BB*TT)   // 4096
#define VD 1280      // qkv fused output width

typedef __attribute__((ext_vector_type(4))) _Float16 f16x4;
typedef __attribute__((ext_vector_type(8))) _Float16 f16x8;
typedef __attribute__((ext_vector_type(4))) float f32x4;

__device__ __forceinline__ void gload16(const void* g, void* l) {
    __builtin_amdgcn_global_load_lds((const __attribute__((address_space(1))) void*)g,
                                     (__attribute__((address_space(3))) void*)l, 16, 0, 0);
}

// ---------------- fp32 -> f16 conversion / packing -------------------------
// xb[4096*1024] <- x ; Wqkvb[1280][1024] <- {W1q,W2q,W1k,W2k,Wv} ;
// Woutb[1024][1024] <- Wout ; biasqkv[1280] = {0 x256, bv}
__global__ __launch_bounds__(256) void convert_kernel(
    const float* __restrict__ x,  const float* __restrict__ W1q,
    const float* __restrict__ W2q, const float* __restrict__ W1k,
    const float* __restrict__ W2k, const float* __restrict__ Wv,
    const float* __restrict__ Wout, const float* __restrict__ bv,
    _Float16* __restrict__ xb, _Float16* __restrict__ Wqkvb,
    _Float16* __restrict__ Woutb, float* __restrict__ biasqkv) {
    int c = blockIdx.x * 256 + threadIdx.x;   // chunk of 8 elements
    if (c < 819200) {
        const float* src; _Float16* dst; int off;
        if      (c < 524288) { src = x;    dst = xb;              off = c; }
        else if (c < 532480) { src = W1q;  dst = Wqkvb;           off = c - 524288; }
        else if (c < 540672) { src = W2q;  dst = Wqkvb + 65536;   off = c - 532480; }
        else if (c < 548864) { src = W1k;  dst = Wqkvb + 131072;  off = c - 540672; }
        else if (c < 557056) { src = W2k;  dst = Wqkvb + 196608;  off = c - 548864; }
        else if (c < 688128) { src = Wv;   dst = Wqkvb + 262144;  off = c - 557056; }
        else                 { src = Wout; dst = Woutb;           off = c - 688128; }
        float4 v0 = *(const float4*)(src + (size_t)off * 8);
        float4 v1 = *(const float4*)(src + (size_t)off * 8 + 4);
        f16x8 h;
        h[0] = (_Float16)v0.x; h[1] = (_Float16)v0.y; h[2] = (_Float16)v0.z; h[3] = (_Float16)v0.w;
        h[4] = (_Float16)v1.x; h[5] = (_Float16)v1.y; h[6] = (_Float16)v1.z; h[7] = (_Float16)v1.w;
        *(f16x8*)(dst + (size_t)off * 8) = h;
    } else if (c < 819360) {
        int col0 = (c - 819200) * 8;
        #pragma unroll
        for (int i = 0; i < 8; ++i) {
            int col = col0 + i;
            biasqkv[col] = (col < 256) ? 0.f : bv[col - 256];
        }
    }
}

// ---------------- f16 MFMA GEMM: C[M,N] = A[M,K] @ W[N,K]^T + bias ---------
// 128x128 tile, BK=32, 4 waves (2x2), global_load_lds staging, swizzled LDS.
__global__ __launch_bounds__(256) void gemm_f16_mfma(
    const _Float16* __restrict__ A, const _Float16* __restrict__ W,
    const float* __restrict__ bias, float* __restrict__ C, int N, int K) {
    __shared__ __attribute__((aligned(16))) _Float16 As[128 * 32];
    __shared__ __attribute__((aligned(16))) _Float16 Ws[128 * 32];
    const int tid = threadIdx.x;
    const int w = tid >> 6, lane = tid & 63;
    const int la = lane >> 4, lb = lane & 15;
    const int bm = blockIdx.x * 128, bn = blockIdx.y * 128;
    const int wr = w >> 1, wc = w & 1;

    // staging chunks: c -> LDS slot (row = c>>2, slot = c&3); global kchunk
    // kg = slot ^ ((row>>1)&3)  [XOR swizzle, both sides]
    const int c0 = tid, c1 = tid + 256;
    const int r0 = c0 >> 2, kg0 = (c0 & 3) ^ ((r0 >> 1) & 3);
    const int r1 = c1 >> 2, kg1 = (c1 & 3) ^ ((r1 >> 1) & 3);
    const _Float16* Ag0 = A + (size_t)(bm + r0) * K + kg0 * 8;
    const _Float16* Ag1 = A + (size_t)(bm + r1) * K + kg1 * 8;
    const _Float16* Wg0 = W + (size_t)(bn + r0) * K + kg0 * 8;
    const _Float16* Wg1 = W + (size_t)(bn + r1) * K + kg1 * 8;
    _Float16* Al0 = &As[(w * 64) * 8];          // wave-uniform LDS bases
    _Float16* Al1 = &As[(256 + w * 64) * 8];
    _Float16* Wl0 = &Ws[(w * 64) * 8];
    _Float16* Wl1 = &Ws[(256 + w * 64) * 8];

    f32x4 acc[4][4] = {};

    // fragment LDS offsets (swizzled read side)
    int aoff[4], boff[4];
    #pragma unroll
    for (int t = 0; t < 4; ++t) {
        int ra = wr * 64 + t * 16 + lb;
        aoff[t] = ra * 32 + (la ^ ((ra >> 1) & 3)) * 8;
        int rb = wc * 64 + t * 16 + lb;
        boff[t] = rb * 32 + (la ^ ((rb >> 1) & 3)) * 8;
    }

    for (int k0 = 0; k0 < K; k0 += 32) {
        gload16(Ag0 + k0, Al0);
        gload16(Ag1 + k0, Al1);
        gload16(Wg0 + k0, Wl0);
        gload16(Wg1 + k0, Wl1);
        __syncthreads();
        f16x8 af[4], bf[4];
        #pragma unroll
        for (int t = 0; t < 4; ++t) af[t] = *(const f16x8*)&As[aoff[t]];
        #pragma unroll
        for (int t = 0; t < 4; ++t) bf[t] = *(const f16x8*)&Ws[boff[t]];
        #pragma unroll
        for (int mt = 0; mt < 4; ++mt)
            #pragma unroll
            for (int nt = 0; nt < 4; ++nt)
                acc[mt][nt] = __builtin_amdgcn_mfma_f32_16x16x32_f16(
                    af[mt], bf[nt], acc[mt][nt], 0, 0, 0);
        __syncthreads();
    }

    #pragma unroll
    for (int nt = 0; nt < 4; ++nt) {
        int col = bn + wc * 64 + nt * 16 + lb;
        float bval = bias ? bias[col] : 0.f;
        #pragma unroll
        for (int mt = 0; mt < 4; ++mt) {
            int row = bm + wr * 64 + mt * 16 + la * 4;
            #pragma unroll
            for (int i = 0; i < 4; ++i)
                C[(size_t)(row + i) * N + col] = acc[mt][nt][i] + bval;
        }
    }
}

// ---------------- exterior (Plucker) + normalize; fold J6 & scale into K --
__device__ __forceinline__ void ext6(const float* a, const float* b, float* L) {
    L[0] = a[0]*b[1] - a[1]*b[0];
    L[1] = a[0]*b[2] - a[2]*b[0];
    L[2] = a[0]*b[3] - a[3]*b[0];
    L[3] = a[1]*b[2] - a[2]*b[1];
    L[4] = a[1]*b[3] - a[3]*b[1];
    L[5] = a[2]*b[3] - a[3]*b[2];
}

__global__ __launch_bounds__(256) void exterior_kernel(const float* __restrict__ Cqkv,
                                                       float* __restrict__ Lq,
                                                       float* __restrict__ JK) {
    int idx = blockIdx.x * 256 + threadIdx.x;     // over BT*HH
    if (idx >= BT * HH) return;
    int bt = idx >> 4, h = idx & 15;
    int b = bt >> 11, t = bt & (TT - 1);
    size_t obase = ((size_t)(b * HH + h) * TT + t) * 6;
    const float* row = Cqkv + (size_t)bt * VD + h * 4;
    float a[4], bb[4], L[6];
    #pragma unroll
    for (int i = 0; i < 4; ++i) { a[i] = row[i]; bb[i] = row[64 + i]; }
    ext6(a, bb, L);
    float s = 0.f;
    #pragma unroll
    for (int c = 0; c < 6; ++c) s += L[c] * L[c];
    float inv = 1.0f / fmaxf(sqrtf(s), 1e-12f);
    #pragma unroll
    for (int c = 0; c < 6; ++c) Lq[obase + c] = L[c] * inv;

    #pragma unroll
    for (int i = 0; i < 4; ++i) { a[i] = row[128 + i]; bb[i] = row[192 + i]; }
    ext6(a, bb, L);
    s = 0.f;
    #pragma unroll
    for (int c = 0; c < 6; ++c) s += L[c] * L[c];
    const float SCALE = 0.40824829046386307f;     // 6^-0.5
    inv = SCALE / fmaxf(sqrtf(s), 1e-12f);
    float* o = JK + obase;
    o[0] =  L[5] * inv;
    o[1] = -L[4] * inv;
    o[2] =  L[3] * inv;
    o[3] =  L[2] * inv;
    o[4] = -L[1] * inv;
    o[5] =  L[0] * inv;
}

// ---------------- MFMA flash attention ------------------------------------
// grid (TT/64, B*H); 256 thr = 4 waves; wave w owns q rows q0+16w..+15.
// |score| <= 6^-0.5 so p=exp(s) is bounded: no online max needed.
// S^T MFMA output layout IS the B-fragment layout of the PV MFMA.
__global__ __launch_bounds__(256) void flash_mfma_kernel(const float* __restrict__ Lq,
                                                         const float* __restrict__ JK,
                                                         const float* __restrict__ V,
                                                         _Float16* __restrict__ O) {
    const int qb = blockIdx.x;
    const int bh = blockIdx.y;            // b*16 + h
    const int b = bh >> 4, h = bh & 15;
    const int tid = threadIdx.x;
    const int w = tid >> 6, lane = tid & 63;
    const int la = lane >> 4, lb = lane & 15;
    const int q0 = qb * 64;
    const int qw = q0 + w * 16;

    __shared__ __attribute__((aligned(16))) _Float16 jk_s[64][8];   // [key][c], c6,7=0
    __shared__ __attribute__((aligned(16))) _Float16 vt_s[64 * 64]; // [d][key^swz]
    __shared__ __attribute__((aligned(16))) _Float16 zrow[8];

    if (tid < 8) zrow[tid] = (_Float16)0.f;
    for (int i = tid; i < 64; i += 256) { jk_s[i][6] = (_Float16)0.f; jk_s[i][7] = (_Float16)0.f; }

    f16x4 blq = {(_Float16)0.f, (_Float16)0.f, (_Float16)0.f, (_Float16)0.f};
    {
        const float* p = Lq + ((size_t)bh * TT + qw + lb) * 6;
        if (la == 0) { blq[0] = (_Float16)p[0]; blq[1] = (_Float16)p[1];
                       blq[2] = (_Float16)p[2]; blq[3] = (_Float16)p[3]; }
        else if (la == 1) { blq[0] = (_Float16)p[4]; blq[1] = (_Float16)p[5]; }
    }

    f32x4 acc[4] = {};
    float lsum = 0.f;
    const int qmask = qw + lb;

    const int vkey = tid >> 2;
    const int vcb  = (tid & 3) * 16;

    const int ntiles = qb + 1;
    for (int t = 0; t < ntiles; ++t) {
        const int k0 = t * 64;
        const float* jkg = JK + ((size_t)bh * TT + k0) * 6;
        for (int i = tid; i < 384; i += 256) {
            int key = i / 6, c = i - key * 6;
            jk_s[key][c] = (_Float16)jkg[i];
        }
        {
            const float* vg = V + (size_t)(b * TT + k0 + vkey) * VD + h * DHEAD + vcb;
            #pragma unroll
            for (int jj = 0; jj < 4; ++jj) {
                float4 v4 = *(const float4*)(vg + jj * 4);
                int d0 = vcb + jj * 4;
                vt_s[(d0+0)*64 + (vkey ^ (((d0+0)&7)<<3))] = (_Float16)v4.x;
                vt_s[(d0+1)*64 + (vkey ^ (((d0+1)&7)<<3))] = (_Float16)v4.y;
                vt_s[(d0+2)*64 + (vkey ^ (((d0+2)&7)<<3))] = (_Float16)v4.z;
                vt_s[(d0+3)*64 + (vkey ^ (((d0+3)&7)<<3))] = (_Float16)v4.w;
            }
        }
        __syncthreads();

        #pragma unroll
        for (int n = 0; n < 4; ++n) {
            if (k0 + n * 16 <= qw + 15) {
                const _Float16* ap = (la < 2) ? &jk_s[n * 16 + lb][la * 4] : zrow;
                f16x4 ajk = *(const f16x4*)ap;
                f32x4 st = __builtin_amdgcn_mfma_f32_16x16x16f16(
                    ajk, blq, (f32x4){0.f, 0.f, 0.f, 0.f}, 0, 0, 0);
                f16x4 pt;
                #pragma unroll
                for (int i = 0; i < 4; ++i) {
                    int key = k0 + n * 16 + la * 4 + i;
                    float p = __expf(st[i]);
                    p = (key <= qmask) ? p : 0.f;
                    lsum += p;
                    pt[i] = (_Float16)p;
                }
                #pragma unroll
                for (int m = 0; m < 4; ++m) {
                    int d = m * 16 + lb;
                    const _Float16* vp = &vt_s[d * 64 + ((n * 16 + la * 4) ^ ((d & 7) << 3))];
                    f16x4 av = *(const f16x4*)vp;
                    acc[m] = __builtin_amdgcn_mfma_f32_16x16x16f16(av, pt, acc[m], 0, 0, 0);
                }
            }
        }
        __syncthreads();
    }

    lsum += __shfl_xor(lsum, 16);
    lsum += __shfl_xor(lsum, 32);
    float inv = 1.f / lsum;
    const int q = qw + lb;
    #pragma unroll
    for (int m = 0; m < 4; ++m) {
        f16x4 o4 = { (_Float16)(acc[m][0] * inv), (_Float16)(acc[m][1] * inv),
                     (_Float16)(acc[m][2] * inv), (_Float16)(acc[m][3] * inv) };
        *(f16x4*)&O[(size_t)(b * TT + q) * DD + h * DHEAD + m * 16 + la * 4] = o4;
    }
}

extern "C" void kernel_launch(void* const* d_in, const int* in_sizes, int n_in,
                              void* d_out, int out_size, void* d_ws, size_t ws_size,
                              hipStream_t stream) {
    const float* x    = (const float*)d_in[0];
    const float* W1q  = (const float*)d_in[1];
    const float* W2q  = (const float*)d_in[2];
    const float* W1k  = (const float*)d_in[3];
    const float* W2k  = (const float*)d_in[4];
    const float* Wv   = (const float*)d_in[5];
    const float* bv   = (const float*)d_in[6];
    const float* Wout = (const float*)d_in[7];
    const float* bout = (const float*)d_in[8];
    float* out = (float*)d_out;

    char* wsb = (char*)d_ws;
    float*     Cqkv    = (float*)wsb;                      // 4096*1280*4 = 20,971,520
    float*     Lq      = (float*)(wsb + 20971520);         // 1,572,864
    float*     JK      = (float*)(wsb + 22544384);         // 1,572,864
    _Float16*  AObf    = (_Float16*)(wsb + 24117248);      // 8,388,608
    _Float16*  xb      = (_Float16*)(wsb + 32505856);      // 8,388,608
    _Float16*  Wqkvb   = (_Float16*)(wsb + 40894464);      // 2,621,440
    _Float16*  Woutb   = (_Float16*)(wsb + 43515904);      // 2,097,152
    float*     biasqkv = (float*)(wsb + 45613056);         // 5,120

    // 1. fp32 -> f16 pack (x, fused QKV weight, Wout, fused bias)
    convert_kernel<<<dim3(3201), 256, 0, stream>>>(
        x, W1q, W2q, W1k, W2k, Wv, Wout, bv, xb, Wqkvb, Woutb, biasqkv);
    // 2. fused qkv projection: Cqkv = xb @ Wqkvb^T + biasqkv   [4096,1280]
    gemm_f16_mfma<<<dim3(BT / 128, VD / 128), 256, 0, stream>>>(
        xb, Wqkvb, biasqkv, Cqkv, VD, DD);
    // 3. Plucker lines (+ J6 & scale folded into K side)
    exterior_kernel<<<dim3(BT * HH / 256), 256, 0, stream>>>(Cqkv, Lq, JK);
    // 4. causal flash attention (f16 MFMA), writes f16 AO
    flash_mfma_kernel<<<dim3(TT / 64, BB * HH), 256, 0, stream>>>(
        Lq, JK, Cqkv + 256, AObf);
    // 5. output projection
    gemm_f16_mfma<<<dim3(BT / 128, DD / 128), 256, 0, stream>>>(
        AObf, Woutb, bout, out, DD, DD);
}